// Round 11
// baseline (475.323 us; speedup 1.0000x reference)
//
#include <hip/hip_runtime.h>
#include <hip/hip_bf16.h>

#define NB 32768
#define DIN 512
#define DHID 4096
#define DOUT 512

typedef __attribute__((ext_vector_type(8))) __bf16 bf16x8;
typedef __attribute__((ext_vector_type(4))) float f32x4;

__device__ __forceinline__ unsigned short f2bf(float f) {
  unsigned u = __builtin_bit_cast(unsigned, f);
  u += 0x7FFFu + ((u >> 16) & 1u);
  return (unsigned short)(u >> 16);
}

__device__ __forceinline__ void gload16(void* lds, const void* g) {
  __builtin_amdgcn_global_load_lds(
      (const __attribute__((address_space(1))) void*)g,
      (__attribute__((address_space(3))) void*)lds, 16, 0, 0);
}

// ---------------- prep: xn = bf16((x - mean)/std) ----------------
__global__ __launch_bounds__(256) void k_prep_x(
    const float4* __restrict__ x, const float* __restrict__ mean,
    const float* __restrict__ stdv, ushort4* __restrict__ xn) {
  const int i = blockIdx.x * 256 + threadIdx.x;
  const int col = (i << 2) & (DIN - 1);
  const float4 v = x[i];
  const float4 m = *(const float4*)(mean + col);
  const float4 s = *(const float4*)(stdv + col);
  ushort4 o;
  o.x = f2bf((v.x - m.x) / s.x);
  o.y = f2bf((v.y - m.y) / s.y);
  o.z = f2bf((v.z - m.z) / s.z);
  o.w = f2bf((v.w - m.w) / s.w);
  xn[i] = o;
}

// ---------------- generic f32 -> bf16 convert ----------------
__global__ __launch_bounds__(256) void k_cvt(
    const float4* __restrict__ in, ushort4* __restrict__ out) {
  const int i = blockIdx.x * 256 + threadIdx.x;
  const float4 v = in[i];
  ushort4 o;
  o.x = f2bf(v.x); o.y = f2bf(v.y); o.z = f2bf(v.z); o.w = f2bf(v.w);
  out[i] = o;
}

// ---------------- GEMM1: h = relu(xn @ W1^T + b1), phase-split ring -------
// R3-proven geometry: tile 256x128x64, 8 waves (4x2), wave 64x64, 3-slot
// 48 KB ring (distance-2), XOR swizzle ((row&7)<<4), counted vmcnt(6).
// NEW: each K-tile = 2 phases {8x ds_read (one ks); issue 3 stage loads;
// sched_barrier; s_barrier; lgkmcnt(0); sched_barrier; setprio(1) 16 MFMA
// setprio(0); s_barrier}, vmcnt(6) before phase 1's barrier (tile t+1
// landed; t+2's 6 loads stay in flight). Pure code motion vs R3 —
// identical slot/ring/wait guarantees.
__global__ __launch_bounds__(512, 2) void k_gemm1(
    const unsigned short* __restrict__ A, const unsigned short* __restrict__ W,
    const float* __restrict__ bias, unsigned short* __restrict__ outp,
    const int N, const int K, const int nbn) {
  __shared__ __align__(16) char lds[3 * 49152];
  const int tid = threadIdx.x;
  const int wave = tid >> 6, lane = tid & 63;
  const int wm = wave >> 1, wn = wave & 1;  // 4x2 wave grid
  const int lidlo = lane & 15, lidhi = lane >> 4;

  const int nwg = (int)gridDim.x;
  const int wg = (int)blockIdx.x;
  const int q = nwg >> 3, r = nwg & 7;
  const int xcd = wg & 7, loc = wg >> 3;
  const int swz = (xcd < r ? xcd * (q + 1) : r * (q + 1) + (xcd - r) * q) + loc;
  const int bm = swz / nbn, bn = swz % nbn;
  const int R0 = bm * 256, C0 = bn * 128;

  const int NT = K >> 6;
  const int dbase0 = wave * 1024;

  // one stage load: part i (0..5) of tile t into slot s (4 A + 2 B chunks)
  auto STAGE1 = [&](int t, int s, int i) {
    char* as = lds + s * 49152;
    const int k0 = t << 6;
    if (i < 4) {
      const int db = i * 8192 + dbase0;
      const int d = db + lane * 16;
      const int row = d >> 7;
      const int colb = (d & 127) ^ ((row & 7) << 4);
      gload16(as + db,
              (const char*)A + ((size_t)(R0 + row) * K + k0) * 2 + colb);
    } else {
      const int db = (i - 4) * 8192 + dbase0;
      const int d = db + lane * 16;
      const int row = d >> 7;
      const int colb = (d & 127) ^ ((row & 7) << 4);
      gload16(as + 32768 + db,
              (const char*)W + ((size_t)(C0 + row) * K + k0) * 2 + colb);
    }
  };

  f32x4 acc[4][4] = {};

#pragma unroll
  for (int i = 0; i < 6; ++i) STAGE1(0, 0, i);
#pragma unroll
  for (int i = 0; i < 6; ++i) STAGE1(1, 1, i);
  asm volatile("s_waitcnt vmcnt(6)" ::: "memory");  // tile 0 landed
  __builtin_amdgcn_s_barrier();

  int slot = 0;
  for (int t = 0; t < NT; ++t) {
    const int nslot = (slot == 2) ? 0 : slot + 1;
    const int sslot = (nslot == 2) ? 0 : nslot + 1;
    const char* as = lds + slot * 49152;
    const char* bs = as + 32768;
    const bool pf = (t + 2 < NT);

#pragma unroll
    for (int kk = 0; kk < 2; ++kk) {
      // phase kk: ds_read this ks's fragments
      bf16x8 af[4], bw[4];
#pragma unroll
      for (int i = 0; i < 4; ++i) {
        const int ra = wm * 64 + i * 16 + lidlo;
        af[i] = *(const bf16x8*)(
            as + ra * 128 + ((kk * 64 + lidhi * 16) ^ ((ra & 7) << 4)));
        const int rb = wn * 64 + i * 16 + lidlo;
        bw[i] = *(const bf16x8*)(
            bs + rb * 128 + ((kk * 64 + lidhi * 16) ^ ((rb & 7) << 4)));
      }
      // issue 3 of tile t+2's stage loads this phase
      if (pf) {
#pragma unroll
        for (int i = 0; i < 3; ++i) STAGE1(t + 2, sslot, kk * 3 + i);
      }
      __builtin_amdgcn_sched_barrier(0);
      if (kk == 1) {
        if (pf) {
          // tile t+1 landed; t+2's 6 loads stay in flight (never drain)
          asm volatile("s_waitcnt vmcnt(6)" ::: "memory");
        } else {
          asm volatile("s_waitcnt vmcnt(0)" ::: "memory");
        }
      }
      __builtin_amdgcn_s_barrier();
      asm volatile("s_waitcnt lgkmcnt(0)" ::: "memory");
      __builtin_amdgcn_sched_barrier(0);  // rule 18: no MFMA hoist
      __builtin_amdgcn_s_setprio(1);
#pragma unroll
      for (int i = 0; i < 4; ++i)
#pragma unroll
        for (int j = 0; j < 4; ++j)
          acc[i][j] = __builtin_amdgcn_mfma_f32_16x16x32_bf16(
              af[i], bw[j], acc[i][j], 0, 0, 0);
      __builtin_amdgcn_s_setprio(0);
      __builtin_amdgcn_sched_barrier(0);
      __builtin_amdgcn_s_barrier();
    }
    slot = nslot;
  }

  const int m0 = R0 + wm * 64 + (lidhi << 2);
  const int n0 = C0 + wn * 64 + lidlo;
#pragma unroll
  for (int j = 0; j < 4; ++j) {
    const int n = n0 + j * 16;
    const float bv = bias[n];
#pragma unroll
    for (int i = 0; i < 4; ++i) {
#pragma unroll
      for (int rr = 0; rr < 4; ++rr) {
        const int m = m0 + i * 16 + rr;
        float v = fmaxf(acc[i][j][rr] + bv, 0.0f);
        outp[(size_t)m * N + n] = f2bf(v);
      }
    }
  }
}

// ---------------- GEMM2 + fused finalize (R10-proven, unchanged) ----------
__global__ __launch_bounds__(512, 2) void k_gemm2(
    const unsigned short* __restrict__ A, const unsigned short* __restrict__ W,
    const float* __restrict__ bias, const float* __restrict__ x,
    const float* __restrict__ out_mean, const float* __restrict__ out_std,
    const float* __restrict__ in_mean, const int* __restrict__ nmp,
    float* __restrict__ outp, const int K) {
  __shared__ __align__(16) char lds[2 * 81920];
  const int tid = threadIdx.x;
  const int wave = tid >> 6, lane = tid & 63;
  const int wm = wave >> 2, wn = wave & 3;  // 2(M) x 4(N)
  const int lidlo = lane & 15, lidhi = lane >> 4;

  const int nwg = (int)gridDim.x;
  const int wg = (int)blockIdx.x;
  const int q = nwg >> 3, r = nwg & 7;
  const int xcd = wg & 7, loc = wg >> 3;
  const int bm = (xcd < r ? xcd * (q + 1) : r * (q + 1) + (xcd - r) * q) + loc;
  const int R0 = bm * 128;

  const int NT = K >> 6;

  auto STAGE = [&](int t, int s) {
    char* as = lds + s * 81920;
    char* bs = as + 16384;
    const int k0 = t << 6;
#pragma unroll
    for (int i = 0; i < 10; ++i) {
      const int c = wave * 10 + i;  // 0..79
      if (c < 16) {
        const int d = c * 1024 + lane * 16;
        const int row = d >> 7;  // 0..127
        const int colb = (d & 127) ^ ((row & 7) << 4);
        gload16(as + c * 1024,
                (const char*)A + ((size_t)(R0 + row) * K + k0) * 2 + colb);
      } else {
        const int d = (c - 16) * 1024 + lane * 16;
        const int row = d >> 7;  // 0..511
        const int colb = (d & 127) ^ ((row & 7) << 4);
        gload16(bs + (c - 16) * 1024,
                (const char*)W + ((size_t)row * K + k0) * 2 + colb);
      }
    }
  };

  f32x4 acc[4][8] = {};

  STAGE(0, 0);
  asm volatile("s_waitcnt vmcnt(0)" ::: "memory");
  __builtin_amdgcn_s_barrier();

  for (int t = 0; t < NT; ++t) {
    if (t + 1 < NT) STAGE(t + 1, (t + 1) & 1);
    const char* as = lds + (t & 1) * 81920;
    const char* bs = as + 16384;
#pragma unroll
    for (int kk = 0; kk < 2; ++kk) {
      bf16x8 af[4], bw[8];
#pragma unroll
      for (int i = 0; i < 4; ++i) {
        const int ra = wm * 64 + i * 16 + lidlo;
        af[i] = *(const bf16x8*)(
            as + ra * 128 + ((kk * 64 + lidhi * 16) ^ ((ra & 7) << 4)));
      }
#pragma unroll
      for (int j = 0; j < 8; ++j) {
        const int rb = wn * 128 + j * 16 + lidlo;
        bw[j] = *(const bf16x8*)(
            bs + rb * 128 + ((kk * 64 + lidhi * 16) ^ ((rb & 7) << 4)));
      }
      __builtin_amdgcn_s_setprio(1);
#pragma unroll
      for (int i = 0; i < 4; ++i)
#pragma unroll
        for (int j = 0; j < 8; ++j)
          acc[i][j] = __builtin_amdgcn_mfma_f32_16x16x32_bf16(
              af[i], bw[j], acc[i][j], 0, 0, 0);
      __builtin_amdgcn_s_setprio(0);
    }
    asm volatile("s_waitcnt vmcnt(0)" ::: "memory");
    __builtin_amdgcn_s_barrier();
  }
  // all staging LDS reads retired (final barrier) -> reuse LDS for reduce

  // ---- fused finalize ----
  float* red = (float*)lds;  // 4(wn) x 128(row) floats = 2 KB
  const int n0 = wn * 128 + lidlo;
  float bv[8], os[8], omim[8];
#pragma unroll
  for (int j = 0; j < 8; ++j) {
    const int n = n0 + j * 16;
    bv[j] = bias[n];
    os[j] = out_std[n];
    omim[j] = out_mean[n] - in_mean[n];
  }
  const float nm = (float)(*nmp);
  const int lmb = wm * 64 + (lidhi << 2);  // + i*16 + rr = row-in-block

  float scr[4][4];
#pragma unroll
  for (int i = 0; i < 4; ++i) {
#pragma unroll
    for (int rr = 0; rr < 4; ++rr) {
      float s = 0.0f;
#pragma unroll
      for (int j = 0; j < 8; ++j) {
        const float v = acc[i][j][rr] + bv[j];
        acc[i][j][rr] = v;
        s += v * v;
      }
      s += __shfl_xor(s, 1); s += __shfl_xor(s, 2);
      s += __shfl_xor(s, 4); s += __shfl_xor(s, 8);
      scr[i][rr] = s;
    }
  }
  if (lidlo == 0) {
#pragma unroll
    for (int i = 0; i < 4; ++i)
#pragma unroll
      for (int rr = 0; rr < 4; ++rr)
        red[wn * 128 + lmb + i * 16 + rr] = scr[i][rr];
  }
  __syncthreads();
#pragma unroll
  for (int i = 0; i < 4; ++i) {
#pragma unroll
    for (int rr = 0; rr < 4; ++rr) {
      const int lm = lmb + i * 16 + rr;
      const float t = red[lm] + red[128 + lm] + red[256 + lm] + red[384 + lm];
      const float rn = sqrtf(t);
      scr[i][rr] = (rn > nm) ? (nm / rn) : 1.0f;
    }
  }
  __syncthreads();

  float s2a[4][4];
#pragma unroll
  for (int i = 0; i < 4; ++i) {
#pragma unroll
    for (int rr = 0; rr < 4; ++rr) {
      const int row = R0 + lmb + i * 16 + rr;
      const float sc = scr[i][rr];
      float s = 0.0f;
#pragma unroll
      for (int j = 0; j < 8; ++j) {
        const int n = n0 + j * 16;
        const float mv = acc[i][j][rr] * sc * os[j] + omim[j] +
                         x[(size_t)row * DOUT + n];
        acc[i][j][rr] = mv;
        s += mv * mv;
      }
      s += __shfl_xor(s, 1); s += __shfl_xor(s, 2);
      s += __shfl_xor(s, 4); s += __shfl_xor(s, 8);
      s2a[i][rr] = s;
    }
  }
  if (lidlo == 0) {
#pragma unroll
    for (int i = 0; i < 4; ++i)
#pragma unroll
      for (int rr = 0; rr < 4; ++rr)
        red[wn * 128 + lmb + i * 16 + rr] = s2a[i][rr];
  }
  __syncthreads();
#pragma unroll
  for (int i = 0; i < 4; ++i) {
#pragma unroll
    for (int rr = 0; rr < 4; ++rr) {
      const int lm = lmb + i * 16 + rr;
      const float t = red[lm] + red[128 + lm] + red[256 + lm] + red[384 + lm];
      const float inv = 1.0f / fmaxf(sqrtf(t), 1e-12f);
      const int row = R0 + lm;
#pragma unroll
      for (int j = 0; j < 8; ++j) {
        const int n = n0 + j * 16;
        outp[(size_t)row * DOUT + n] = acc[i][j][rr] * inv;
      }
    }
  }
}

extern "C" void kernel_launch(void* const* d_in, const int* in_sizes, int n_in,
                              void* d_out, int out_size, void* d_ws, size_t ws_size,
                              hipStream_t stream) {
  const float* x = (const float*)d_in[0];
  const float* in_mean = (const float*)d_in[1];
  const float* in_std = (const float*)d_in[2];
  const float* out_mean = (const float*)d_in[3];
  const float* out_std = (const float*)d_in[4];
  const float* W1 = (const float*)d_in[5];
  const float* b1 = (const float*)d_in[6];
  const float* W2 = (const float*)d_in[7];
  const float* b2 = (const float*)d_in[8];
  const int* nmp = (const int*)d_in[9];
  float* out = (float*)d_out;

  // ---- workspace layout (adaptive: h holds only `chunk` batch rows) ----
  char* ws = (char*)d_ws;
  unsigned short* xn = (unsigned short*)ws;   ws += (size_t)NB * DIN * 2;    // 32 MB
  unsigned short* W1b = (unsigned short*)ws;  ws += (size_t)DHID * DIN * 2;  //  4 MB
  unsigned short* W2b = (unsigned short*)ws;  ws += (size_t)DOUT * DHID * 2; //  4 MB
  unsigned short* h = (unsigned short*)ws;    // chunk * DHID bf16

  const size_t fixedB = (size_t)(ws - (char*)d_ws);
  const size_t avail = (ws_size > fixedB) ? (ws_size - fixedB) : 0;
  long long crows = (long long)(avail / ((size_t)DHID * 2));
  if (crows > NB) crows = NB;
  crows &= ~255LL;                 // multiple of 256 (BM of GEMM1)
  if (crows < 256) crows = 256;
  const int chunk = (int)crows;

  // 1) xn = bf16((x - in_mean)/in_std)
  k_prep_x<<<16384, 256, 0, stream>>>((const float4*)x, in_mean, in_std,
                                      (ushort4*)xn);
  // 2) W1, W2 -> bf16
  k_cvt<<<2048, 256, 0, stream>>>((const float4*)W1, (ushort4*)W1b);
  k_cvt<<<2048, 256, 0, stream>>>((const float4*)W2, (ushort4*)W2b);

  // 3) per-chunk: h = relu(xn@W1^T + b1); out = finalize(h@W2^T + b2, x)
  for (int s = 0; s < NB; s += chunk) {
    const int mc = (NB - s < chunk) ? (NB - s) : chunk;
    const int g1 = (mc / 256) * (DHID / 128);
    k_gemm1<<<g1, 512, 0, stream>>>(xn + (size_t)s * DIN, W1b, b1, h,
                                    DHID, DIN, DHID / 128);
    const int g2 = mc / 128;
    k_gemm2<<<g2, 512, 0, stream>>>(h, W2b, b2, x + (size_t)s * DIN,
                                    out_mean, out_std, in_mean, nmp,
                                    out + (size_t)s * DOUT, DHID);
  }
}